// Round 11
// baseline (609.367 us; speedup 1.0000x reference)
//
#include <hip/hip_runtime.h>
#include <hip/hip_bf16.h>

#define B_  4
#define T_  2048
#define D_  2048
#define H_  16
#define DH_ 128

typedef __attribute__((ext_vector_type(4))) float f32x4;
typedef __attribute__((ext_vector_type(8))) short short8;
typedef __attribute__((ext_vector_type(4))) _Float16 half4;

__device__ __forceinline__ ushort f2bf(float f) {
    unsigned int u = __builtin_bit_cast(unsigned int, f);
    u += 0x7fffu + ((u >> 16) & 1u);   // RNE
    return (ushort)(u >> 16);
}
__device__ __forceinline__ ushort f2h(float f) {
    return (ushort)(__builtin_bit_cast(unsigned int, __builtin_amdgcn_cvt_pkrtz(f, f)) & 0xffffu);
}

// async global -> LDS, 16B per lane. LDS dst must be wave-uniform base + lane*16.
__device__ __forceinline__ void glds16(const void* g, void* l) {
    __builtin_amdgcn_global_load_lds(
        (const __attribute__((address_space(1))) unsigned int*)g,
        (__attribute__((address_space(3))) unsigned int*)l, 16, 0, 0);
}

// ------------------------------------------------- fused prep: cast x->bf16 + 4x W transpose
__global__ void prep_kernel(
    const float* __restrict__ x, ushort* __restrict__ xb,
    const float* __restrict__ W0, const float* __restrict__ W1,
    const float* __restrict__ W2, const float* __restrict__ W3,
    ushort* __restrict__ T0, ushort* __restrict__ T1,
    ushort* __restrict__ T2, ushort* __restrict__ T3)
{
    __shared__ float tile[32][33];
    const int z = blockIdx.z;
    int tx = threadIdx.x, ty = threadIdx.y;           // 32 x 8
    if (z == 4) {
        int blk = blockIdx.y * 64 + blockIdx.x;
        int tid = ty * 32 + tx;
        size_t base = (size_t)blk * 4096 + tid * 4;
#pragma unroll
        for (int k2 = 0; k2 < 4; ++k2) {
            float4 v = *(const float4*)(x + base + k2 * 1024);
            ushort4 o;
            o.x = f2bf(v.x); o.y = f2bf(v.y); o.z = f2bf(v.z); o.w = f2bf(v.w);
            *(ushort4*)(xb + base + k2 * 1024) = o;
        }
        return;
    }
    const float* W = (z == 0) ? W0 : (z == 1) ? W1 : (z == 2) ? W2 : W3;
    ushort* Wt     = (z == 0) ? T0 : (z == 1) ? T1 : (z == 2) ? T2 : T3;
    int n0 = blockIdx.x * 32, k0 = blockIdx.y * 32;
#pragma unroll
    for (int i = 0; i < 4; i++)
        tile[ty + i * 8][tx] = W[(size_t)(k0 + ty + i * 8) * D_ + n0 + tx];
    __syncthreads();
#pragma unroll
    for (int i = 0; i < 4; i++)
        Wt[(size_t)(n0 + ty + i * 8) * D_ + k0 + tx] = f2bf(tile[tx][ty + i * 8]);
}

// ---------------------------------------------------------------- merged QKV GEMM (128^2, proven)
// R10: reverted to the R8 single-buffer body — R9's dbuf was null (identical 255 us /
// 36% MfmaUtil; the m97 2-barrier structure is the ceiling; stop touching this kernel).
__global__ __launch_bounds__(256, 3) void gemm_qkv(
    const ushort* __restrict__ A,
    const ushort* __restrict__ Wq, const ushort* __restrict__ Wk, const ushort* __restrict__ Wv,
    const float* __restrict__ bq, const float* __restrict__ bk, const float* __restrict__ bv,
    ushort* __restrict__ Qb, ushort* __restrict__ Kb, ushort* __restrict__ Vtb,
    float qscale)
{
    extern __shared__ char smem[];
    uint4* sA = (uint4*)smem;              // [128 rows][4 chunks], slot c holds chunk c^sw(row)
    uint4* sB = (uint4*)(smem + 8192);

    const int tid  = threadIdx.x;
    const int sel  = blockIdx.x >> 4;           // 0=Q 1=K 2=V
    const int row0 = blockIdx.y * 128, col0 = (blockIdx.x & 15) * 128;
    const ushort* Bt = (sel == 0) ? Wq : (sel == 1) ? Wk : Wv;
    const float* bias = (sel == 0) ? bq : (sel == 1) ? bk : bv;
    const float oscale = (sel == 0) ? qscale : 1.0f;
    const int K = D_, N = D_;

    const int mA = tid >> 2, g = tid & 3;
    const int gc = g ^ ((mA >> 2) & 3);
    const ushort* pa0 = A  + (size_t)(row0 + mA) * K + gc * 8;
    const ushort* pb0 = Bt + (size_t)(col0 + mA) * K + gc * 8;

    const int lane = tid & 63, w = tid >> 6;
    const int l15 = lane & 15, quad = lane >> 4;
    const int wm = w & 1, wn = w >> 1;
    const int csel = quad ^ ((l15 >> 2) & 3);
    int aoff[4], boff[4];
#pragma unroll
    for (int mt = 0; mt < 4; mt++) aoff[mt] = (wm * 64 + mt * 16 + l15) * 4 + csel;
#pragma unroll
    for (int nt = 0; nt < 4; nt++) boff[nt] = (wn * 64 + nt * 16 + l15) * 4 + csel;

    f32x4 acc[4][4] = {};

    const int kIter = K >> 5;
    for (int kt = 0; kt < kIter; ++kt) {
        if (kt) __syncthreads();
        glds16(pa0 + kt * 32,                     sA + tid);
        glds16(pa0 + kt * 32 + (size_t)64 * K,    sA + tid + 256);
        glds16(pb0 + kt * 32,                     sB + tid);
        glds16(pb0 + kt * 32 + (size_t)64 * K,    sB + tid + 256);
        __syncthreads();
        short8 af[4], bfr[4];
#pragma unroll
        for (int mt = 0; mt < 4; mt++) af[mt]  = __builtin_bit_cast(short8, sA[aoff[mt]]);
#pragma unroll
        for (int nt = 0; nt < 4; nt++) bfr[nt] = __builtin_bit_cast(short8, sB[boff[nt]]);
#pragma unroll
        for (int mt = 0; mt < 4; mt++)
#pragma unroll
            for (int nt = 0; nt < 4; nt++)
                acc[mt][nt] = __builtin_amdgcn_mfma_f32_16x16x32_bf16(af[mt], bfr[nt], acc[mt][nt], 0, 0, 0);
    }

    if (sel < 2) {
        ushort* Cout = (sel == 0) ? Qb : Kb;
#pragma unroll
        for (int nt = 0; nt < 4; nt++) {
            int col = col0 + wn * 64 + nt * 16 + l15;
            float bb = bias[col];
#pragma unroll
            for (int mt = 0; mt < 4; mt++) {
                int rowb = row0 + wm * 64 + mt * 16 + quad * 4;
#pragma unroll
                for (int r = 0; r < 4; ++r)
                    Cout[(size_t)(rowb + r) * N + col] = f2bf((acc[mt][nt][r] + bb) * oscale);
            }
        }
    } else {
        // V path: transpose 128x128 tile through LDS, emit f16 [B,H,DH,T]
        __syncthreads();
        ushort* tr = (ushort*)smem;        // [128 dh][136]
#pragma unroll
        for (int nt = 0; nt < 4; nt++) {
            int cl = wn * 64 + nt * 16 + l15;
            float bb = bias[col0 + cl];
#pragma unroll
            for (int mt = 0; mt < 4; mt++) {
                int rl = wm * 64 + mt * 16 + quad * 4;
#pragma unroll
                for (int r = 0; r < 4; ++r)
                    tr[cl * 136 + rl + r] = f2h(acc[mt][nt][r] + bb);
            }
        }
        __syncthreads();
        int b = row0 >> 11, t0 = row0 & (T_ - 1), h = col0 >> 7;
        for (int idx = tid; idx < 2048; idx += 256) {
            int dh = idx >> 4, c = idx & 15;
            uint4 v = *(const uint4*)(tr + dh * 136 + c * 8);
            *(uint4*)(Vtb + (size_t)((b * H_ + h) * DH_ + dh) * T_ + t0 + c * 8) = v;
        }
    }
}

// ---------------------------------------------------------------- O-projection GEMM (f32 out)
// (256,4): 60 VGPR + 64 AGPR = 124 <= 128 cap; 1024 blocks = exactly 1 occupancy round.
__global__ __launch_bounds__(256, 4) void gemm_bt_f32(
    const ushort* __restrict__ A, const ushort* __restrict__ Bt,
    const float* __restrict__ bias, float* __restrict__ Cout,
    int M, int N, int K)
{
    extern __shared__ char smem[];
    uint4* sA = (uint4*)smem;
    uint4* sB = (uint4*)(smem + 8192);

    const int tid  = threadIdx.x;
    const int row0 = blockIdx.y * 128, col0 = blockIdx.x * 128;

    const int mA = tid >> 2, g = tid & 3;
    const int gc = g ^ ((mA >> 2) & 3);
    const ushort* pa0 = A  + (size_t)(row0 + mA) * K + gc * 8;
    const ushort* pb0 = Bt + (size_t)(col0 + mA) * K + gc * 8;

    const int lane = tid & 63, w = tid >> 6;
    const int l15 = lane & 15, quad = lane >> 4;
    const int wm = w & 1, wn = w >> 1;
    const int csel = quad ^ ((l15 >> 2) & 3);
    int aoff[4], boff[4];
#pragma unroll
    for (int mt = 0; mt < 4; mt++) aoff[mt] = (wm * 64 + mt * 16 + l15) * 4 + csel;
#pragma unroll
    for (int nt = 0; nt < 4; nt++) boff[nt] = (wn * 64 + nt * 16 + l15) * 4 + csel;

    f32x4 acc[4][4] = {};

    const int kIter = K >> 5;
    for (int kt = 0; kt < kIter; ++kt) {
        if (kt) __syncthreads();
        glds16(pa0 + kt * 32,                     sA + tid);
        glds16(pa0 + kt * 32 + (size_t)64 * K,    sA + tid + 256);
        glds16(pb0 + kt * 32,                     sB + tid);
        glds16(pb0 + kt * 32 + (size_t)64 * K,    sB + tid + 256);
        __syncthreads();
        short8 af[4], bfr[4];
#pragma unroll
        for (int mt = 0; mt < 4; mt++) af[mt]  = __builtin_bit_cast(short8, sA[aoff[mt]]);
#pragma unroll
        for (int nt = 0; nt < 4; nt++) bfr[nt] = __builtin_bit_cast(short8, sB[boff[nt]]);
#pragma unroll
        for (int mt = 0; mt < 4; mt++)
#pragma unroll
            for (int nt = 0; nt < 4; nt++)
                acc[mt][nt] = __builtin_amdgcn_mfma_f32_16x16x32_bf16(af[mt], bfr[nt], acc[mt][nt], 0, 0, 0);
    }

#pragma unroll
    for (int nt = 0; nt < 4; nt++) {
        int col = col0 + wn * 64 + nt * 16 + l15;
        float bb = bias[col];
#pragma unroll
        for (int mt = 0; mt < 4; mt++) {
            int rowb = row0 + wm * 64 + mt * 16 + quad * 4;
#pragma unroll
            for (int r = 0; r < 4; ++r)
                Cout[(size_t)(rowb + r) * N + col] = acc[mt][nt][r] + bb;
        }
    }
}

// ---------------------------------------------------------------- flash attention (S^T / O^T form)
// Q (pre-scaled by 1/sqrt(DH)*log2e), K: [B,T,D] bf16 ; Vt: [B,H,DH,T] f16 ; O: [B,T,D] bf16
// R10 (on the R8-proven 1-q-tile/block structure, 2048 blocks, 5 blocks/CU):
//  - V staging via glds16, SINGLE-buffered (LDS stays 32 KiB): deletes the per-tile
//    global->VGPR->LDS roundtrip (4 loads + 8 ds_write_b64/thread, ~10% of the LDS pipe).
//    LDS 16B-slot c of row dh holds global chunk c^(dh&7) (inverse swizzle on the global
//    source, LDS dst linear). PV reads half4 at off=(((s8>>1)^(l15&7))<<3)+((s8&1)<<2).
//  - Defer-max (T13): skip accO rescale when __all(rmax <= mrow+8); P bounded by 2^8.
__global__ __launch_bounds__(256, 5) void attn_kernel(
    const ushort* __restrict__ Q, const ushort* __restrict__ K,
    const ushort* __restrict__ Vt, ushort* __restrict__ O)
{
    __shared__ __align__(16) char smem[32768];
    uint4*  kS = (uint4*)smem;                 // [64 s][16 chunks], chunk-swizzled
    ushort* vS = (ushort*)(smem + 16384);      // [128 dh][8 slot16], slot ^ (dh&7)

    const int tid = threadIdx.x;
    const int bid = blockIdx.x;                // 0..2047
    const int r  = bid >> 3;                   // 0..255
    const int g  = (bid & 7) + 8 * (r & 7);    // head-group 0..63 ; xcd = bid&7
    const int qt = 31 - (r >> 3);              // 31..0: long blocks first
    const int b = g >> 4, h = g & 15;

    const int lane = tid & 63, w = tid >> 6, l15 = lane & 15, quad = lane >> 4;

    const int krow = tid >> 4;                       // 0..15
    const int kchunk = (tid & 15) ^ (krow & 7);
    const ushort* kg = K + ((size_t)(b * T_) + krow) * D_ + h * DH_ + kchunk * 8;

    // V via glds16: thread covers row (tid>>3) of each 32-dh j-block, 16B slot (tid&7);
    // global source slot pre-swizzled so LDS slot c holds chunk c^(dh&7).
    const int vdh = tid >> 3;                        // 0..31
    const int vslot = (tid & 7) ^ (vdh & 7);
    const ushort* vg = Vt + ((size_t)((b * H_ + h) * DH_) + vdh) * T_ + vslot * 8;
    char* vdst = smem + 16384 + tid * 16;

    const int q0 = qt * 64;
    const int qbase = q0 + w * 16;               // wave's first q

    short8 aq[4];
    {
        const ushort* qp = Q + ((size_t)(b * T_) + qbase + l15) * D_ + h * DH_ + quad * 8;
#pragma unroll
        for (int ks = 0; ks < 4; ++ks)
            aq[ks] = __builtin_bit_cast(short8, *(const uint4*)(qp + ks * 32));
    }

    f32x4 accO[8] = {};                          // O^T[dh=nt*16+quad*4+r][q=l15]
    float mrow = -INFINITY, lrow = 0.f;

    auto tile = [&](int s0, int stMax, bool diag) {
        __syncthreads();                          // prior tile's readers done (WAR)
        const ushort* kp = kg + (size_t)s0 * D_;
#pragma unroll
        for (int j = 0; j < 4; ++j) glds16(kp + (size_t)j * 16 * D_, kS + j * 256 + tid);
        const ushort* vp = vg + s0;
#pragma unroll
        for (int j = 0; j < 4; ++j) glds16(vp + (size_t)j * 32 * T_, vdst + j * 4096);
        __syncthreads();                          // tile ready (vmcnt0 drained pre-barrier)

        f32x4 sT[4] = {};
#pragma unroll
        for (int ks = 0; ks < 4; ++ks)
#pragma unroll
            for (int st = 0; st < 4; ++st)
                if (st < stMax) {
                    int row = st * 16 + l15;
                    short8 ak = __builtin_bit_cast(short8, kS[row * 16 + ((ks * 4 + quad) ^ (row & 7))]);
                    sT[st] = __builtin_amdgcn_mfma_f32_16x16x32_bf16(ak, aq[ks], sT[st], 0, 0, 0);
                }

        if (diag) {
            const int q = qbase + l15;
            const int st = stMax - 1;
#pragma unroll
            for (int r2 = 0; r2 < 4; ++r2)
                if (s0 + st * 16 + quad * 4 + r2 > q) sT[st][r2] = -INFINITY;
        }

        float rmax = -INFINITY;
#pragma unroll
        for (int st = 0; st < 4; ++st)
            if (st < stMax)
#pragma unroll
                for (int r2 = 0; r2 < 4; ++r2) rmax = fmaxf(rmax, sT[st][r2]);
        rmax = fmaxf(rmax, __shfl_xor(rmax, 16));
        rmax = fmaxf(rmax, __shfl_xor(rmax, 32));
        if (!__all(rmax <= mrow + 8.0f)) {        // defer-max: rescale only on real growth
            float mnew  = fmaxf(mrow, rmax);
            float alpha = __builtin_amdgcn_exp2f(mrow - mnew);
            mrow = mnew;
            lrow *= alpha;
#pragma unroll
            for (int nt = 0; nt < 8; ++nt)
#pragma unroll
                for (int r2 = 0; r2 < 4; ++r2) accO[nt][r2] *= alpha;
        }

        float psum = 0.f;
        half4 pb[4];
#pragma unroll
        for (int st = 0; st < 4; ++st)
            if (st < stMax) {
                float p0 = __builtin_amdgcn_exp2f(sT[st][0] - mrow);
                float p1 = __builtin_amdgcn_exp2f(sT[st][1] - mrow);
                float p2 = __builtin_amdgcn_exp2f(sT[st][2] - mrow);
                float p3 = __builtin_amdgcn_exp2f(sT[st][3] - mrow);
                psum += (p0 + p1) + (p2 + p3);
                uint2 u;
                u.x = __builtin_bit_cast(unsigned int, __builtin_amdgcn_cvt_pkrtz(p0, p1));
                u.y = __builtin_bit_cast(unsigned int, __builtin_amdgcn_cvt_pkrtz(p2, p3));
                pb[st] = __builtin_bit_cast(half4, u);
            }
        psum += __shfl_xor(psum, 16);
        psum += __shfl_xor(psum, 32);
        lrow += psum;

        // O^T += V P^T : half4 at slot (s8>>1)^(dh&7), half-within (s8&1)
#pragma unroll
        for (int st = 0; st < 4; ++st)
            if (st < stMax) {
                const int s8 = st * 4 + quad;
                const int off = (((s8 >> 1) ^ (l15 & 7)) << 3) + ((s8 & 1) << 2);
#pragma unroll
                for (int nt = 0; nt < 8; ++nt) {
                    int dh = nt * 16 + l15;
                    half4 vf = *(const half4*)(vS + dh * 64 + off);
                    accO[nt] = __builtin_amdgcn_mfma_f32_16x16x16f16(vf, pb[st], accO[nt], 0, 0, 0);
                }
            }
    };

    for (int it = 0; it < qt; ++it) tile(it * 64, 4, false);
    tile(qt * 64, w + 1, true);

    // epilogue: transpose O^T -> O via wave-private LDS, write bf16
    __syncthreads();                              // all waves done reading kS/vS
    ushort* eT = (ushort*)smem + w * 2176;        // [16 q][136 dh-pad]
    float inv = 1.0f / lrow;
#pragma unroll
    for (int nt = 0; nt < 8; ++nt) {
        int dh = nt * 16 + quad * 4;
#pragma unroll
        for (int r2 = 0; r2 < 4; ++r2)
            eT[l15 * 136 + dh + r2] = f2bf(accO[nt][r2] * inv);
    }
    for (int idx = lane; idx < 256; idx += 64) {
        int row = idx >> 4, c = idx & 15;
        uint4 v = *(const uint4*)(eT + row * 136 + c * 8);
        *(uint4*)(O + ((size_t)(b * T_) + q0 + w * 16 + row) * D_ + h * DH_ + c * 8) = v;
    }
}

extern "C" void kernel_launch(void* const* d_in, const int* in_sizes, int n_in,
                              void* d_out, int out_size, void* d_ws, size_t ws_size,
                              hipStream_t stream) {
    const float* x  = (const float*)d_in[0];
    const float* Wq = (const float*)d_in[1];
    const float* bq = (const float*)d_in[2];
    const float* Wk = (const float*)d_in[3];
    const float* bk = (const float*)d_in[4];
    const float* Wv = (const float*)d_in[5];
    const float* bv = (const float*)d_in[6];
    const float* Wo = (const float*)d_in[7];
    const float* bo = (const float*)d_in[8];

    char* ws = (char*)d_ws;
    const size_t MB = 1u << 20;
    ushort* xb  = (ushort*)(ws);
    ushort* Wqt = (ushort*)(ws + 32 * MB);
    ushort* Wkt = (ushort*)(ws + 40 * MB);
    ushort* Wvt = (ushort*)(ws + 48 * MB);
    ushort* Wot = (ushort*)(ws + 56 * MB);
    ushort* Qb  = (ushort*)(ws + 64 * MB);
    ushort* Kb  = (ushort*)(ws + 96 * MB);
    ushort* Vtb = (ushort*)(ws + 128 * MB);
    ushort* Ob  = (ushort*)(ws + 160 * MB);

    const int M = B_ * T_;   // 8192
    const float qscale = (float)(0.08838834764831845 * 1.4426950408889634); // 1/sqrt(DH) * log2(e)

    dim3 tb(32, 8), tg(D_ / 32, D_ / 32, 5);
    prep_kernel<<<tg, tb, 0, stream>>>(x, xb, Wq, Wk, Wv, Wo, Wqt, Wkt, Wvt, Wot);

    gemm_qkv<<<dim3(48, M / 128), 256, 34816, stream>>>(
        xb, Wqt, Wkt, Wvt, bq, bk, bv, Qb, Kb, Vtb, qscale);

    attn_kernel<<<dim3(2048), 256, 0, stream>>>(Qb, Kb, Vtb, Ob);

    gemm_bt_f32<<<dim3(D_ / 128, M / 128), 256, 16384, stream>>>(
        Ob, Wot, bo, (float*)d_out, M, D_, D_);
}